// Round 7
// baseline (484.260 us; speedup 1.0000x reference)
//
#include <hip/hip_runtime.h>

#define NN 100000
#define NE 1600000
#define D 128
#define LEAKY 0.01f
#define BNEPS 1e-5f

#define G 256        // sort groups (workgroups)
#define CHUNK 6250   // NE / G exactly
#define B 782        // ceil(NN/128) dst-buckets
#define BSHIFT 7
#define BMASK 127

typedef short v8s __attribute__((ext_vector_type(8)));
typedef float v4f __attribute__((ext_vector_type(4)));

// round-to-nearest-even f32 -> bf16 (returns low 16 bits)
__device__ __forceinline__ unsigned f2bf(float f) {
    unsigned u = __float_as_uint(f);
    return (u + 0x7fffu + ((u >> 16) & 1u)) >> 16;
}
__device__ __forceinline__ float bf2f(unsigned h) {
    return __uint_as_float(h << 16);
}

// ---------------- counting sort by dst bucket ----------------
// hist[b*G + g] = #edges in group g hitting bucket b (bucket-major for scan)

__global__ __launch_bounds__(256) void hist_kernel(const int* __restrict__ dst,
                                                   int* __restrict__ hist) {
    __shared__ int h[B];
    for (int i = threadIdx.x; i < B; i += 256) h[i] = 0;
    __syncthreads();
    int g = blockIdx.x;
    const int* dp = dst + g * CHUNK;
    for (int k = threadIdx.x; k < CHUNK; k += 256)
        atomicAdd(&h[dp[k] >> BSHIFT], 1);
    __syncthreads();
    for (int i = threadIdx.x; i < B; i += 256) hist[i * G + g] = h[i];
}

__global__ void scanA(const int* __restrict__ a, int* __restrict__ bsum) {
    __shared__ int sm[256];
    int t = threadIdx.x;
    sm[t] = a[blockIdx.x * 256 + t];
    __syncthreads();
    for (int s = 128; s > 0; s >>= 1) {
        if (t < s) sm[t] += sm[t + s];
        __syncthreads();
    }
    if (t == 0) bsum[blockIdx.x] = sm[0];
}

__global__ void scanB(const int* __restrict__ bsum, int* __restrict__ boffs) {
    int lane = threadIdx.x;
    int run = 0;
    for (int base = 0; base < B; base += 64) {
        int i = base + lane;
        int v = (i < B) ? bsum[i] : 0;
        int orig = v;
        for (int off = 1; off < 64; off <<= 1) {
            int t = __shfl_up(v, off);
            if (lane >= off) v += t;
        }
        if (i < B) boffs[i] = run + v - orig;   // exclusive
        run += __shfl(v, 63);
    }
}

__global__ void scanC(const int* __restrict__ a, const int* __restrict__ boffs,
                      int* __restrict__ offs) {
    __shared__ int sm[256];
    int t = threadIdx.x;
    int i = blockIdx.x * 256 + t;
    int v = a[i];
    sm[t] = v;
    __syncthreads();
    for (int off = 1; off < 256; off <<= 1) {
        int x = (t >= off) ? sm[t - off] : 0;
        __syncthreads();
        sm[t] += x;
        __syncthreads();
    }
    offs[i] = boffs[blockIdx.x] + sm[t] - v;    // exclusive
}

// sort by dst bucket + out-degree atomics fused (atomic drain overlaps the
// streaming scatter; standalone deg kernel was 66 us of pure atomic stall)

__global__ __launch_bounds__(256) void sort_kernel(const int* __restrict__ src,
                                                   const int* __restrict__ dst,
                                                   const int* __restrict__ offs,
                                                   unsigned* __restrict__ ebuf,
                                                   int* __restrict__ deg) {
    __shared__ int cur[B];
    int g = blockIdx.x;
    for (int i = threadIdx.x; i < B; i += 256) cur[i] = offs[i * G + g];
    __syncthreads();
    const int* sp = src + g * CHUNK;
    const int* dp = dst + g * CHUNK;
    for (int k = threadIdx.x; k < CHUNK; k += 256) {
        int d = dp[k], s = sp[k];
        atomicAdd(&deg[s], 1);                       // out-degree (overlapped)
        int pos = atomicAdd(&cur[d >> BSHIFT], 1);
        ebuf[pos] = ((unsigned)(d & BMASK) << 17) | (unsigned)s;   // src < 2^17
    }
}

// ---------------- norm_s + x*norm_s -> bf16 gather source (fused) ----------------

__global__ __launch_bounds__(256) void conv_kernel(const float* __restrict__ x,
                                                   const int* __restrict__ deg,
                                                   float* __restrict__ norm_s,
                                                   unsigned* __restrict__ hb) {
    int t = blockIdx.x * 256 + threadIdx.x;     // one u32 pair per thread
    if (t >= NN * 64) return;
    int row = t >> 6;
    float ns = rsqrtf((float)(deg[row] + 1));   // +1 = self-loop
    if ((t & 63) == 0) norm_s[row] = ns;
    float2 v = ((const float2*)x)[t];
    hb[t] = f2bf(v.x * ns) | (f2bf(v.y * ns) << 16);
}

// ---------------- per-bucket local sort: bucket order -> per-node CSR ----------

__global__ __launch_bounds__(256) void local_sort(
    const int* __restrict__ offs, unsigned* __restrict__ ebuf,
    int* __restrict__ row, float* __restrict__ norm_d)
{
    __shared__ int cnt[128];
    __shared__ int sc[128];
    const int b = blockIdx.x;
    const int t = threadIdx.x;
    const int s = offs[b * G];
    const int e = (b == B - 1) ? NE : offs[(b + 1) * G];
    if (t < 128) cnt[t] = 0;
    __syncthreads();

    unsigned ent[16];   // 16*256 = 4096 capacity; bucket mean 2048, sd ~45
    int nent = 0;
    for (int k = s + t; k < e && nent < 16; k += 256) {
        unsigned u = ebuf[k];
        ent[nent++] = u;
        atomicAdd(&cnt[u >> 17], 1);
    }
    __syncthreads();

    if (t < 128) sc[t] = cnt[t];
    __syncthreads();
    for (int off = 1; off < 128; off <<= 1) {
        int v = 0;
        if (t < 128 && t >= off) v = sc[t - off];
        __syncthreads();
        if (t < 128) sc[t] += v;
        __syncthreads();
    }
    if (t < 128) {
        int st = s + sc[t] - cnt[t];   // exclusive start
        int node = b * 128 + t;
        if (node < NN) {
            row[node] = st;
            norm_d[node] = rsqrtf((float)(cnt[t] + 1));
        }
        cnt[t] = st;                   // becomes cursor
    }
    if (b == B - 1 && t == 0) row[NN] = NE;
    __syncthreads();

    for (int i = 0; i < nent; ++i) {
        unsigned u = ent[i];
        int pos = atomicAdd(&cnt[u >> 17], 1);
        ebuf[pos] = u & 0x1FFFFu;      // strip bucket bits -> plain src id
    }
}

// ---------------- CSR gather-aggregate over bf16 rows, fp32 accumulate --------
// 16 gathers in flight per lane; output split bf16 hi/lo planes for MFMA GEMM.

__global__ __launch_bounds__(256) void csr_agg(
    const int* __restrict__ row, const int* __restrict__ csr,
    const unsigned* __restrict__ hp,
    unsigned* __restrict__ Ahi, unsigned* __restrict__ Alo)
{
    int i = blockIdx.x * 4 + (threadIdx.x >> 6);
    if (i >= NN) return;
    int lane = threadIdx.x & 63;

    float2 acc;
    {
        unsigned u = hp[(size_t)i * 64 + lane];
        acc.x = __uint_as_float(u << 16);
        acc.y = __uint_as_float(u & 0xffff0000u);
    }

    int start = row[i], end = row[i + 1];
    for (int base = start; base < end; base += 64) {
        int n = end - base; if (n > 64) n = 64;
        int sv = csr[base + (lane < n ? lane : n - 1)];
        int j = 0;
        for (; j + 16 <= n; j += 16) {
            unsigned uu[16];
            #pragma unroll
            for (int t = 0; t < 16; ++t) {
                int s = __shfl(sv, j + t);
                uu[t] = hp[(size_t)s * 64 + lane];
            }
            #pragma unroll
            for (int t = 0; t < 16; ++t) {
                acc.x += __uint_as_float(uu[t] << 16);
                acc.y += __uint_as_float(uu[t] & 0xffff0000u);
            }
        }
        for (; j < n; ++j) {
            int s = __shfl(sv, j);
            unsigned u = hp[(size_t)s * 64 + lane];
            acc.x += __uint_as_float(u << 16);
            acc.y += __uint_as_float(u & 0xffff0000u);
        }
    }
    unsigned hx = f2bf(acc.x), hy = f2bf(acc.y);
    float lx = acc.x - bf2f(hx), ly = acc.y - bf2f(hy);
    Ahi[(size_t)i * 64 + lane] = hx | (hy << 16);
    Alo[(size_t)i * 64 + lane] = f2bf(lx) | (f2bf(ly) << 16);
}

// ---------------- MFMA GEMM, split-precision bf16 (3-mfma ~ fp32 accuracy) -----

template<bool LAYER0>
__global__ __launch_bounds__(256) void gemm_kernel(
    const unsigned* __restrict__ Ahi_g, const unsigned* __restrict__ Alo_g,
    const float* __restrict__ W, const float* __restrict__ bias,
    const float* __restrict__ norm_s, const float* __restrict__ norm_d,
    const float* __restrict__ gamma, const float* __restrict__ beta,
    const float* __restrict__ rmean, const float* __restrict__ rvar,
    float* __restrict__ outf, unsigned short* __restrict__ outb)
{
    __shared__ unsigned lhi[64 * 68];   // 64 rows x 136 bf16 (pad 8)
    __shared__ unsigned llo[64 * 68];

    const int w    = threadIdx.x >> 6;
    const int lane = threadIdx.x & 63;
    const int quad = lane >> 4;
    const int l16  = lane & 15;

    // ---- B fragments (hi/lo) for this wave's 2 col-tiles, all K ----
    v8s Bhi[2][4], Blo[2][4];
    int col[2];
    #pragma unroll
    for (int ct = 0; ct < 2; ++ct) {
        col[ct] = 32 * w + 16 * ct + l16;
        #pragma unroll
        for (int q = 0; q < 4; ++q) {
            int kb = 32 * q + quad * 8;
            v8s hi8, lo8;
            #pragma unroll
            for (int kk = 0; kk < 8; ++kk) {
                float wv = W[(kb + kk) * D + col[ct]];
                unsigned h = f2bf(wv);
                hi8[kk] = (short)h;
                lo8[kk] = (short)f2bf(wv - bf2f(h));
            }
            Bhi[ct][q] = hi8;
            Blo[ct][q] = lo8;
        }
    }

    // per-column epilogue constants
    float bcol[2], s[2] = {0.f, 0.f}, sh[2] = {0.f, 0.f};
    #pragma unroll
    for (int ct = 0; ct < 2; ++ct) {
        bcol[ct] = bias[col[ct]];
        if (LAYER0) {
            s[ct]  = gamma[col[ct]] * rsqrtf(rvar[col[ct]] + BNEPS);
            sh[ct] = beta[col[ct]] - rmean[col[ct]] * s[ct];
        }
    }

    for (int row0 = blockIdx.x * 64; row0 < NN; row0 += gridDim.x * 64) {
        __syncthreads();
        for (int idx = threadIdx.x; idx < 64 * 64; idx += 256) {
            int r = idx >> 6, cp = idx & 63;
            int rw = row0 + r;
            unsigned vh = 0, vl = 0;
            if (rw < NN) {
                vh = Ahi_g[(size_t)rw * 64 + cp];
                vl = Alo_g[(size_t)rw * 64 + cp];
            }
            lhi[r * 68 + cp] = vh;
            llo[r * 68 + cp] = vl;
        }
        __syncthreads();

        #pragma unroll
        for (int rt = 0; rt < 4; ++rt) {
            v4f acc0 = {0.f, 0.f, 0.f, 0.f};
            v4f acc1 = {0.f, 0.f, 0.f, 0.f};
            #pragma unroll
            for (int q = 0; q < 4; ++q) {
                const unsigned short* ph = (const unsigned short*)lhi
                    + (rt * 16 + l16) * 136 + q * 32 + quad * 8;
                const unsigned short* pl = (const unsigned short*)llo
                    + (rt * 16 + l16) * 136 + q * 32 + quad * 8;
                v8s ahi = *(const v8s*)ph;
                v8s alo = *(const v8s*)pl;
                acc0 = __builtin_amdgcn_mfma_f32_16x16x32_bf16(ahi, Bhi[0][q], acc0, 0, 0, 0);
                acc0 = __builtin_amdgcn_mfma_f32_16x16x32_bf16(alo, Bhi[0][q], acc0, 0, 0, 0);
                acc0 = __builtin_amdgcn_mfma_f32_16x16x32_bf16(ahi, Blo[0][q], acc0, 0, 0, 0);
                acc1 = __builtin_amdgcn_mfma_f32_16x16x32_bf16(ahi, Bhi[1][q], acc1, 0, 0, 0);
                acc1 = __builtin_amdgcn_mfma_f32_16x16x32_bf16(alo, Bhi[1][q], acc1, 0, 0, 0);
                acc1 = __builtin_amdgcn_mfma_f32_16x16x32_bf16(ahi, Blo[1][q], acc1, 0, 0, 0);
            }
            #pragma unroll
            for (int r = 0; r < 4; ++r) {
                int rw = row0 + rt * 16 + quad * 4 + r;
                if (rw >= NN) continue;
                float nd = norm_d[rw];
                float o0 = acc0[r] * nd + bcol[0];
                float o1 = acc1[r] * nd + bcol[1];
                if (LAYER0) {
                    o0 = o0 * s[0] + sh[0];
                    o1 = o1 * s[1] + sh[1];
                    o0 = o0 > 0.f ? o0 : LEAKY * o0;
                    o1 = o1 > 0.f ? o1 : LEAKY * o1;
                    float ns = norm_s[rw];
                    o0 *= ns; o1 *= ns;
                    outb[(size_t)rw * D + col[0]] = (unsigned short)f2bf(o0);
                    outb[(size_t)rw * D + col[1]] = (unsigned short)f2bf(o1);
                } else {
                    outf[(size_t)rw * D + col[0]] = o0;
                    outf[(size_t)rw * D + col[1]] = o1;
                }
            }
        }
    }
}

// ---------------- launch ----------------

extern "C" void kernel_launch(void* const* d_in, const int* in_sizes, int n_in,
                              void* d_out, int out_size, void* d_ws, size_t ws_size,
                              hipStream_t stream) {
    const float* x     = (const float*)d_in[0];
    const int*   src   = (const int*)d_in[1];
    const int*   dst   = (const int*)d_in[2];
    const float* W1    = (const float*)d_in[3];
    const float* b1    = (const float*)d_in[4];
    const float* W2    = (const float*)d_in[5];
    const float* b2    = (const float*)d_in[6];
    const float* gamma = (const float*)d_in[7];
    const float* beta  = (const float*)d_in[8];
    const float* rmean = (const float*)d_in[9];
    const float* rvar  = (const float*)d_in[10];
    float* out = (float*)d_out;

    // bf16 gather-source scratch lives in d_out's first half (dead until the
    // final GEMM overwrites all of d_out with fp32 results).
    unsigned* hb = (unsigned*)d_out;                    // NN*64 u32 = 25.6 MB

    // ws layout (4B units)
    unsigned* Ahi   = (unsigned*)d_ws;                  // NN*64 u32 (bf16 hi pairs)
    unsigned* Alo   = Ahi + (size_t)NN * 64;            // NN*64 u32 (bf16 lo pairs)
    float*    norm  = (float*)(Alo + (size_t)NN * 64);  // 2N f32
    int*      deg   = (int*)(norm + 2 * NN);            // N int (out-degree)
    int*      hist  = deg + NN;                         // B*G int; row[] aliases after scanC
    int*      offs  = hist + B * G;                     // B*G int
    int*      bsum  = offs + B * G;                     // B int
    int*      boffs = bsum + B;                         // B int
    unsigned* ebuf  = (unsigned*)(boffs + B);           // NE u32
    float* norm_s = norm;
    float* norm_d = norm + NN;
    int*   row    = hist;                // aliases hist (dead after scanC)

    hipMemsetAsync(deg, 0, NN * sizeof(int), stream);

    // counting sort by dst bucket (+ fused out-degree), then per-bucket local sort
    hist_kernel<<<G, 256, 0, stream>>>(dst, hist);
    scanA<<<B * G / 256, 256, 0, stream>>>(hist, bsum);
    scanB<<<1, 64, 0, stream>>>(bsum, boffs);
    scanC<<<B * G / 256, 256, 0, stream>>>(hist, boffs, offs);
    sort_kernel<<<G, 256, 0, stream>>>(src, dst, offs, ebuf, deg);
    conv_kernel<<<(NN * 64 + 255) / 256, 256, 0, stream>>>(x, deg, norm_s, hb);
    local_sort<<<B, 256, 0, stream>>>(offs, ebuf, row, norm_d);

    const int AGG_BLOCKS = (NN + 3) / 4;
    const int GEMM_BLOCKS = 784;
    // layer 0: agg = selfloop + sum_e xs[src]  -> split bf16 hi/lo
    csr_agg<<<AGG_BLOCKS, 256, 0, stream>>>(row, (const int*)ebuf, hb, Ahi, Alo);
    gemm_kernel<true><<<GEMM_BLOCKS, 256, 0, stream>>>(Ahi, Alo, W1, b1,
                                                       norm_s, norm_d,
                                                       gamma, beta, rmean, rvar,
                                                       nullptr, (unsigned short*)hb);
    // layer 1: gather source = bf16 hs (norm_src folded)
    csr_agg<<<AGG_BLOCKS, 256, 0, stream>>>(row, (const int*)ebuf, hb, Ahi, Alo);
    gemm_kernel<false><<<GEMM_BLOCKS, 256, 0, stream>>>(Ahi, Alo, W2, b2,
                                                        norm_s, norm_d,
                                                        nullptr, nullptr, nullptr, nullptr,
                                                        out, nullptr);
}

// Round 8
// 479.071 us; speedup vs baseline: 1.0108x; 1.0108x over previous
//
#include <hip/hip_runtime.h>

#define NN 100000
#define NE 1600000
#define D 128
#define LEAKY 0.01f
#define BNEPS 1e-5f

#define G 256        // sort groups (workgroups)
#define CHUNK 6250   // NE / G exactly
#define B 782        // ceil(NN/128) dst-buckets
#define BSHIFT 7
#define BMASK 127

typedef short v8s __attribute__((ext_vector_type(8)));
typedef float v4f __attribute__((ext_vector_type(4)));

// round-to-nearest-even f32 -> bf16 (returns low 16 bits)
__device__ __forceinline__ unsigned f2bf(float f) {
    unsigned u = __float_as_uint(f);
    return (u + 0x7fffu + ((u >> 16) & 1u)) >> 16;
}
__device__ __forceinline__ float bf2f(unsigned h) {
    return __uint_as_float(h << 16);
}

// ---------------- counting sort by dst bucket + fused out-degree ----------------
// hist[b*G + g] = #edges in group g hitting bucket b (bucket-major for scan).
// deg atomics fused HERE (read-bound kernel): the fabric atomic drain overlaps
// the dst/src streaming reads + LDS counting, unlike in sort (write-bound).

__global__ __launch_bounds__(256) void hist_kernel(const int* __restrict__ src,
                                                   const int* __restrict__ dst,
                                                   int* __restrict__ deg,
                                                   int* __restrict__ hist) {
    __shared__ int h[B];
    for (int i = threadIdx.x; i < B; i += 256) h[i] = 0;
    __syncthreads();
    int g = blockIdx.x;
    const int* dp = dst + g * CHUNK;
    const int* sp = src + g * CHUNK;
    for (int k = threadIdx.x; k < CHUNK; k += 256) {
        atomicAdd(&h[dp[k] >> BSHIFT], 1);
        atomicAdd(&deg[sp[k]], 1);          // out-degree (overlapped with reads)
    }
    __syncthreads();
    for (int i = threadIdx.x; i < B; i += 256) hist[i * G + g] = h[i];
}

__global__ void scanA(const int* __restrict__ a, int* __restrict__ bsum) {
    __shared__ int sm[256];
    int t = threadIdx.x;
    sm[t] = a[blockIdx.x * 256 + t];
    __syncthreads();
    for (int s = 128; s > 0; s >>= 1) {
        if (t < s) sm[t] += sm[t + s];
        __syncthreads();
    }
    if (t == 0) bsum[blockIdx.x] = sm[0];
}

__global__ void scanB(const int* __restrict__ bsum, int* __restrict__ boffs) {
    int lane = threadIdx.x;
    int run = 0;
    for (int base = 0; base < B; base += 64) {
        int i = base + lane;
        int v = (i < B) ? bsum[i] : 0;
        int orig = v;
        for (int off = 1; off < 64; off <<= 1) {
            int t = __shfl_up(v, off);
            if (lane >= off) v += t;
        }
        if (i < B) boffs[i] = run + v - orig;   // exclusive
        run += __shfl(v, 63);
    }
}

__global__ void scanC(const int* __restrict__ a, const int* __restrict__ boffs,
                      int* __restrict__ offs) {
    __shared__ int sm[256];
    int t = threadIdx.x;
    int i = blockIdx.x * 256 + t;
    int v = a[i];
    sm[t] = v;
    __syncthreads();
    for (int off = 1; off < 256; off <<= 1) {
        int x = (t >= off) ? sm[t - off] : 0;
        __syncthreads();
        sm[t] += x;
        __syncthreads();
    }
    offs[i] = boffs[blockIdx.x] + sm[t] - v;    // exclusive
}

__global__ __launch_bounds__(256) void sort_kernel(const int* __restrict__ src,
                                                   const int* __restrict__ dst,
                                                   const int* __restrict__ offs,
                                                   unsigned* __restrict__ ebuf) {
    __shared__ int cur[B];
    int g = blockIdx.x;
    for (int i = threadIdx.x; i < B; i += 256) cur[i] = offs[i * G + g];
    __syncthreads();
    const int* sp = src + g * CHUNK;
    const int* dp = dst + g * CHUNK;
    for (int k = threadIdx.x; k < CHUNK; k += 256) {
        int d = dp[k], s = sp[k];
        int pos = atomicAdd(&cur[d >> BSHIFT], 1);
        ebuf[pos] = ((unsigned)(d & BMASK) << 17) | (unsigned)s;   // src < 2^17
    }
}

// ---------------- norm_s + x*norm_s -> bf16 gather source (fused) ----------------

__global__ __launch_bounds__(256) void conv_kernel(const float* __restrict__ x,
                                                   const int* __restrict__ deg,
                                                   float* __restrict__ norm_s,
                                                   unsigned* __restrict__ hb) {
    int t = blockIdx.x * 256 + threadIdx.x;     // one u32 pair per thread
    if (t >= NN * 64) return;
    int row = t >> 6;
    float ns = rsqrtf((float)(deg[row] + 1));   // +1 = self-loop
    if ((t & 63) == 0) norm_s[row] = ns;
    float2 v = ((const float2*)x)[t];
    hb[t] = f2bf(v.x * ns) | (f2bf(v.y * ns) << 16);
}

// ---------------- per-bucket local sort: bucket order -> per-node CSR ----------

__global__ __launch_bounds__(256) void local_sort(
    const int* __restrict__ offs, unsigned* __restrict__ ebuf,
    int* __restrict__ row)
{
    __shared__ int cnt[128];
    __shared__ int sc[128];
    const int b = blockIdx.x;
    const int t = threadIdx.x;
    const int s = offs[b * G];
    const int e = (b == B - 1) ? NE : offs[(b + 1) * G];
    if (t < 128) cnt[t] = 0;
    __syncthreads();

    unsigned ent[16];   // 16*256 = 4096 capacity; bucket mean 2048, sd ~45
    int nent = 0;
    for (int k = s + t; k < e && nent < 16; k += 256) {
        unsigned u = ebuf[k];
        ent[nent++] = u;
        atomicAdd(&cnt[u >> 17], 1);
    }
    __syncthreads();

    if (t < 128) sc[t] = cnt[t];
    __syncthreads();
    for (int off = 1; off < 128; off <<= 1) {
        int v = 0;
        if (t < 128 && t >= off) v = sc[t - off];
        __syncthreads();
        if (t < 128) sc[t] += v;
        __syncthreads();
    }
    if (t < 128) {
        int st = s + sc[t] - cnt[t];   // exclusive start
        int node = b * 128 + t;
        if (node < NN) row[node] = st;
        cnt[t] = st;                   // becomes cursor
    }
    if (b == B - 1 && t == 0) row[NN] = NE;
    __syncthreads();

    for (int i = 0; i < nent; ++i) {
        unsigned u = ent[i];
        int pos = atomicAdd(&cnt[u >> 17], 1);
        ebuf[pos] = u & 0x1FFFFu;      // strip bucket bits -> plain src id
    }
}

// ---------------- fused aggregate + MFMA GEMM ----------------
// One block = 64 contiguous nodes. Phase 1: each wave gathers 16 nodes
// (8-wide ILP, fp32 accumulate), writes split bf16 hi/lo rows to LDS, and
// derives norm_d from the CSR range length. Phase 2: 3-mfma split-precision
// GEMM (fp32-equivalent) + epilogue, straight to global. No Ahi/Alo
// round-trip through HBM, no separate gemm launch.
// B-fragments load AFTER phase 1 (latency hides in barrier wait) to keep
// gather-phase VGPR pressure low. launch_bounds(256,4): 128 VGPR cap ->
// 16 waves/CU, matching the 4-blocks/CU LDS limit (2x 17.4 KB).

template<bool LAYER0>
__global__ __launch_bounds__(256, 4) void agg_gemm(
    const int* __restrict__ row, const int* __restrict__ csr,
    const unsigned* __restrict__ hp,
    const float* __restrict__ W, const float* __restrict__ bias,
    const float* __restrict__ norm_s,
    const float* __restrict__ gamma, const float* __restrict__ beta,
    const float* __restrict__ rmean, const float* __restrict__ rvar,
    float* __restrict__ outf, unsigned short* __restrict__ outb)
{
    __shared__ unsigned lhi[64 * 68];   // 64 rows x 136 bf16 (pad 8)
    __shared__ unsigned llo[64 * 68];
    __shared__ float ndl[64];

    const int w    = threadIdx.x >> 6;
    const int lane = threadIdx.x & 63;
    const int quad = lane >> 4;
    const int l16  = lane & 15;
    const int row0 = blockIdx.x * 64;

    // ---- phase 1: aggregate 16 nodes for this wave ----
    for (int t = 0; t < 16; ++t) {
        int i = row0 + 16 * w + t;
        float2 acc = {0.f, 0.f};
        int indeg = 0;
        if (i < NN) {
            unsigned u0 = hp[(size_t)i * 64 + lane];     // self-loop init
            acc.x = bf2f(u0 & 0xffffu);
            acc.y = __uint_as_float(u0 & 0xffff0000u);
            int start = row[i], end = row[i + 1];
            indeg = end - start;
            for (int base = start; base < end; base += 64) {
                int n = end - base; if (n > 64) n = 64;
                int sv = csr[base + (lane < n ? lane : n - 1)];
                int j = 0;
                for (; j + 8 <= n; j += 8) {
                    int ss[8]; unsigned uu[8];
                    #pragma unroll
                    for (int q = 0; q < 8; ++q) ss[q] = __shfl(sv, j + q);
                    #pragma unroll
                    for (int q = 0; q < 8; ++q) uu[q] = hp[(size_t)ss[q] * 64 + lane];
                    #pragma unroll
                    for (int q = 0; q < 8; ++q) {
                        acc.x += __uint_as_float(uu[q] << 16);
                        acc.y += __uint_as_float(uu[q] & 0xffff0000u);
                    }
                }
                for (; j < n; ++j) {
                    int s = __shfl(sv, j);
                    unsigned u = hp[(size_t)s * 64 + lane];
                    acc.x += __uint_as_float(u << 16);
                    acc.y += __uint_as_float(u & 0xffff0000u);
                }
            }
        }
        int r = 16 * w + t;
        unsigned hx = f2bf(acc.x), hy = f2bf(acc.y);
        lhi[r * 68 + lane] = hx | (hy << 16);
        llo[r * 68 + lane] = f2bf(acc.x - bf2f(hx)) | (f2bf(acc.y - bf2f(hy)) << 16);
        if (lane == 0) ndl[r] = rsqrtf((float)(indeg + 1));
    }

    // ---- B fragments (hi/lo) for this wave's 2 col-tiles, all K ----
    v8s Bhi[2][4], Blo[2][4];
    int col[2];
    #pragma unroll
    for (int ct = 0; ct < 2; ++ct) {
        col[ct] = 32 * w + 16 * ct + l16;
        #pragma unroll
        for (int q = 0; q < 4; ++q) {
            int kb = 32 * q + quad * 8;
            v8s hi8, lo8;
            #pragma unroll
            for (int kk = 0; kk < 8; ++kk) {
                float wv = W[(kb + kk) * D + col[ct]];
                unsigned h = f2bf(wv);
                hi8[kk] = (short)h;
                lo8[kk] = (short)f2bf(wv - bf2f(h));
            }
            Bhi[ct][q] = hi8;
            Blo[ct][q] = lo8;
        }
    }
    float bcol[2], s[2] = {0.f, 0.f}, sh[2] = {0.f, 0.f};
    #pragma unroll
    for (int ct = 0; ct < 2; ++ct) {
        bcol[ct] = bias[col[ct]];
        if (LAYER0) {
            s[ct]  = gamma[col[ct]] * rsqrtf(rvar[col[ct]] + BNEPS);
            sh[ct] = beta[col[ct]] - rmean[col[ct]] * s[ct];
        }
    }
    __syncthreads();

    // ---- phase 2: 3-mfma split GEMM on the resident 64-row tile ----
    #pragma unroll
    for (int rt = 0; rt < 4; ++rt) {
        v4f acc0 = {0.f, 0.f, 0.f, 0.f};
        v4f acc1 = {0.f, 0.f, 0.f, 0.f};
        #pragma unroll
        for (int q = 0; q < 4; ++q) {
            const unsigned short* ph = (const unsigned short*)lhi
                + (rt * 16 + l16) * 136 + q * 32 + quad * 8;
            const unsigned short* pl = (const unsigned short*)llo
                + (rt * 16 + l16) * 136 + q * 32 + quad * 8;
            v8s ahi = *(const v8s*)ph;
            v8s alo = *(const v8s*)pl;
            acc0 = __builtin_amdgcn_mfma_f32_16x16x32_bf16(ahi, Bhi[0][q], acc0, 0, 0, 0);
            acc0 = __builtin_amdgcn_mfma_f32_16x16x32_bf16(alo, Bhi[0][q], acc0, 0, 0, 0);
            acc0 = __builtin_amdgcn_mfma_f32_16x16x32_bf16(ahi, Blo[0][q], acc0, 0, 0, 0);
            acc1 = __builtin_amdgcn_mfma_f32_16x16x32_bf16(ahi, Bhi[1][q], acc1, 0, 0, 0);
            acc1 = __builtin_amdgcn_mfma_f32_16x16x32_bf16(alo, Bhi[1][q], acc1, 0, 0, 0);
            acc1 = __builtin_amdgcn_mfma_f32_16x16x32_bf16(ahi, Blo[1][q], acc1, 0, 0, 0);
        }
        #pragma unroll
        for (int r = 0; r < 4; ++r) {
            int lr = rt * 16 + quad * 4 + r;
            int rw = row0 + lr;
            if (rw >= NN) continue;
            float nd = ndl[lr];
            float o0 = acc0[r] * nd + bcol[0];
            float o1 = acc1[r] * nd + bcol[1];
            if (LAYER0) {
                o0 = o0 * s[0] + sh[0];
                o1 = o1 * s[1] + sh[1];
                o0 = o0 > 0.f ? o0 : LEAKY * o0;
                o1 = o1 > 0.f ? o1 : LEAKY * o1;
                float ns = norm_s[rw];
                o0 *= ns; o1 *= ns;
                outb[(size_t)rw * D + col[0]] = (unsigned short)f2bf(o0);
                outb[(size_t)rw * D + col[1]] = (unsigned short)f2bf(o1);
            } else {
                outf[(size_t)rw * D + col[0]] = o0;
                outf[(size_t)rw * D + col[1]] = o1;
            }
        }
    }
}

// ---------------- launch ----------------

extern "C" void kernel_launch(void* const* d_in, const int* in_sizes, int n_in,
                              void* d_out, int out_size, void* d_ws, size_t ws_size,
                              hipStream_t stream) {
    const float* x     = (const float*)d_in[0];
    const int*   src   = (const int*)d_in[1];
    const int*   dst   = (const int*)d_in[2];
    const float* W1    = (const float*)d_in[3];
    const float* b1    = (const float*)d_in[4];
    const float* W2    = (const float*)d_in[5];
    const float* b2    = (const float*)d_in[6];
    const float* gamma = (const float*)d_in[7];
    const float* beta  = (const float*)d_in[8];
    const float* rmean = (const float*)d_in[9];
    const float* rvar  = (const float*)d_in[10];
    float* out = (float*)d_out;

    // ws layout (4B units)
    unsigned* hb    = (unsigned*)d_ws;                  // NN*64 u32: bf16 x*ns (layer-0 src)
    unsigned* hb2   = hb + (size_t)NN * 64;             // NN*64 u32: bf16 activations (layer-1 src)
    float*    norm_s= (float*)(hb2 + (size_t)NN * 64);  // N f32
    int*      deg   = (int*)(norm_s + NN);              // N int (out-degree)
    int*      hist  = deg + NN;                         // B*G int; row[] aliases after scanC
    int*      offs  = hist + B * G;                     // B*G int
    int*      bsum  = offs + B * G;                     // B int
    int*      boffs = bsum + B;                         // B int
    unsigned* ebuf  = (unsigned*)(boffs + B);           // NE u32
    int*      row   = hist;              // aliases hist (dead after scanC)

    hipMemsetAsync(deg, 0, NN * sizeof(int), stream);

    // counting sort by dst bucket (+ fused out-degree in hist), local sort -> CSR
    hist_kernel<<<G, 256, 0, stream>>>(src, dst, deg, hist);
    scanA<<<B * G / 256, 256, 0, stream>>>(hist, bsum);
    scanB<<<1, 64, 0, stream>>>(bsum, boffs);
    scanC<<<B * G / 256, 256, 0, stream>>>(hist, boffs, offs);
    sort_kernel<<<G, 256, 0, stream>>>(src, dst, offs, ebuf);
    conv_kernel<<<(NN * 64 + 255) / 256, 256, 0, stream>>>(x, deg, norm_s, hb);
    local_sort<<<B, 256, 0, stream>>>(offs, ebuf, row);

    const int GEMM_BLOCKS = (NN + 63) / 64;   // 1563
    // layer 0: gather hb -> GEMM(W1) + BN + leaky + norm_s -> bf16 hb2
    agg_gemm<true><<<GEMM_BLOCKS, 256, 0, stream>>>(row, (const int*)ebuf, hb,
                                                    W1, b1, norm_s,
                                                    gamma, beta, rmean, rvar,
                                                    nullptr, (unsigned short*)hb2);
    // layer 1: gather hb2 -> GEMM(W2) -> fp32 out
    agg_gemm<false><<<GEMM_BLOCKS, 256, 0, stream>>>(row, (const int*)ebuf, hb2,
                                                     W2, b2, norm_s,
                                                     nullptr, nullptr, nullptr, nullptr,
                                                     out, nullptr);
}

// Round 9
// 457.570 us; speedup vs baseline: 1.0583x; 1.0470x over previous
//
#include <hip/hip_runtime.h>

#define NN 100000
#define NE 1600000
#define D 128
#define LEAKY 0.01f
#define BNEPS 1e-5f

#define G 256        // sort groups (workgroups)
#define CHUNK 6250   // NE / G exactly
#define B 782        // ceil(NN/128) dst-buckets
#define BSHIFT 7
#define BMASK 127

typedef short v8s __attribute__((ext_vector_type(8)));
typedef float v4f __attribute__((ext_vector_type(4)));

// round-to-nearest-even f32 -> bf16 (returns low 16 bits)
__device__ __forceinline__ unsigned f2bf(float f) {
    unsigned u = __float_as_uint(f);
    return (u + 0x7fffu + ((u >> 16) & 1u)) >> 16;
}
__device__ __forceinline__ float bf2f(unsigned h) {
    return __uint_as_float(h << 16);
}

// ---------------- counting sort by dst bucket + fused out-degree ----------------
// deg atomics fused in this READ-bound kernel (overlaps the streaming reads).
// Round-7 evidence: fusing them into write-bound sort_kernel costs +13 us.

__global__ __launch_bounds__(256) void hist_kernel(const int* __restrict__ src,
                                                   const int* __restrict__ dst,
                                                   int* __restrict__ deg,
                                                   int* __restrict__ hist) {
    __shared__ int h[B];
    for (int i = threadIdx.x; i < B; i += 256) h[i] = 0;
    __syncthreads();
    int g = blockIdx.x;
    const int* dp = dst + g * CHUNK;
    const int* sp = src + g * CHUNK;
    for (int k = threadIdx.x; k < CHUNK; k += 256) {
        atomicAdd(&h[dp[k] >> BSHIFT], 1);
        atomicAdd(&deg[sp[k]], 1);          // out-degree (overlapped with reads)
    }
    __syncthreads();
    for (int i = threadIdx.x; i < B; i += 256) hist[i * G + g] = h[i];
}

__global__ void scanA(const int* __restrict__ a, int* __restrict__ bsum) {
    __shared__ int sm[256];
    int t = threadIdx.x;
    sm[t] = a[blockIdx.x * 256 + t];
    __syncthreads();
    for (int s = 128; s > 0; s >>= 1) {
        if (t < s) sm[t] += sm[t + s];
        __syncthreads();
    }
    if (t == 0) bsum[blockIdx.x] = sm[0];
}

__global__ void scanB(const int* __restrict__ bsum, int* __restrict__ boffs) {
    int lane = threadIdx.x;
    int run = 0;
    for (int base = 0; base < B; base += 64) {
        int i = base + lane;
        int v = (i < B) ? bsum[i] : 0;
        int orig = v;
        for (int off = 1; off < 64; off <<= 1) {
            int t = __shfl_up(v, off);
            if (lane >= off) v += t;
        }
        if (i < B) boffs[i] = run + v - orig;   // exclusive
        run += __shfl(v, 63);
    }
}

__global__ void scanC(const int* __restrict__ a, const int* __restrict__ boffs,
                      int* __restrict__ offs) {
    __shared__ int sm[256];
    int t = threadIdx.x;
    int i = blockIdx.x * 256 + t;
    int v = a[i];
    sm[t] = v;
    __syncthreads();
    for (int off = 1; off < 256; off <<= 1) {
        int x = (t >= off) ? sm[t - off] : 0;
        __syncthreads();
        sm[t] += x;
        __syncthreads();
    }
    offs[i] = boffs[blockIdx.x] + sm[t] - v;    // exclusive
}

__global__ __launch_bounds__(256) void sort_kernel(const int* __restrict__ src,
                                                   const int* __restrict__ dst,
                                                   const int* __restrict__ offs,
                                                   unsigned* __restrict__ ebuf) {
    __shared__ int cur[B];
    int g = blockIdx.x;
    for (int i = threadIdx.x; i < B; i += 256) cur[i] = offs[i * G + g];
    __syncthreads();
    const int* sp = src + g * CHUNK;
    const int* dp = dst + g * CHUNK;
    for (int k = threadIdx.x; k < CHUNK; k += 256) {
        int d = dp[k], s = sp[k];
        int pos = atomicAdd(&cur[d >> BSHIFT], 1);
        ebuf[pos] = ((unsigned)(d & BMASK) << 17) | (unsigned)s;   // src < 2^17
    }
}

// ---------------- norm_s + x*norm_s -> bf16 gather source (fused) ----------------

__global__ __launch_bounds__(256) void conv_kernel(const float* __restrict__ x,
                                                   const int* __restrict__ deg,
                                                   float* __restrict__ norm_s,
                                                   unsigned* __restrict__ hb) {
    int t = blockIdx.x * 256 + threadIdx.x;     // one u32 pair per thread
    if (t >= NN * 64) return;
    int row = t >> 6;
    float ns = rsqrtf((float)(deg[row] + 1));   // +1 = self-loop
    if ((t & 63) == 0) norm_s[row] = ns;
    float2 v = ((const float2*)x)[t];
    hb[t] = f2bf(v.x * ns) | (f2bf(v.y * ns) << 16);
}

// ---------------- per-bucket local sort: bucket order -> per-node CSR ----------

__global__ __launch_bounds__(256) void local_sort(
    const int* __restrict__ offs, unsigned* __restrict__ ebuf,
    int* __restrict__ row, float* __restrict__ norm_d)
{
    __shared__ int cnt[128];
    __shared__ int sc[128];
    const int b = blockIdx.x;
    const int t = threadIdx.x;
    const int s = offs[b * G];
    const int e = (b == B - 1) ? NE : offs[(b + 1) * G];
    if (t < 128) cnt[t] = 0;
    __syncthreads();

    unsigned ent[16];   // 16*256 = 4096 capacity; bucket mean 2048, sd ~45
    int nent = 0;
    for (int k = s + t; k < e && nent < 16; k += 256) {
        unsigned u = ebuf[k];
        ent[nent++] = u;
        atomicAdd(&cnt[u >> 17], 1);
    }
    __syncthreads();

    if (t < 128) sc[t] = cnt[t];
    __syncthreads();
    for (int off = 1; off < 128; off <<= 1) {
        int v = 0;
        if (t < 128 && t >= off) v = sc[t - off];
        __syncthreads();
        if (t < 128) sc[t] += v;
        __syncthreads();
    }
    if (t < 128) {
        int st = s + sc[t] - cnt[t];   // exclusive start
        int node = b * 128 + t;
        if (node < NN) {
            row[node] = st;
            norm_d[node] = rsqrtf((float)(cnt[t] + 1));
        }
        cnt[t] = st;                   // becomes cursor
    }
    if (b == B - 1 && t == 0) row[NN] = NE;
    __syncthreads();

    for (int i = 0; i < nent; ++i) {
        unsigned u = ent[i];
        int pos = atomicAdd(&cnt[u >> 17], 1);
        ebuf[pos] = u & 0x1FFFFu;      // strip bucket bits -> plain src id
    }
}

// ---------------- CSR gather-aggregate over bf16 rows, fp32 accumulate --------
// One wave per node, 8 gathers in flight (proven best: round 6). Output split
// bf16 hi/lo planes for the MFMA GEMM.

__global__ __launch_bounds__(256) void csr_agg(
    const int* __restrict__ row, const int* __restrict__ csr,
    const unsigned* __restrict__ hp,
    unsigned* __restrict__ Ahi, unsigned* __restrict__ Alo)
{
    int i = blockIdx.x * 4 + (threadIdx.x >> 6);
    if (i >= NN) return;
    int lane = threadIdx.x & 63;

    float2 acc;
    {
        unsigned u = hp[(size_t)i * 64 + lane];
        acc.x = __uint_as_float(u << 16);
        acc.y = __uint_as_float(u & 0xffff0000u);
    }

    int start = row[i], end = row[i + 1];
    for (int base = start; base < end; base += 64) {
        int n = end - base; if (n > 64) n = 64;
        int sv = csr[base + (lane < n ? lane : n - 1)];
        int j = 0;
        for (; j + 8 <= n; j += 8) {
            int ss[8]; unsigned uu[8];
            #pragma unroll
            for (int t = 0; t < 8; ++t) ss[t] = __shfl(sv, j + t);
            #pragma unroll
            for (int t = 0; t < 8; ++t) uu[t] = hp[(size_t)ss[t] * 64 + lane];
            #pragma unroll
            for (int t = 0; t < 8; ++t) {
                acc.x += __uint_as_float(uu[t] << 16);
                acc.y += __uint_as_float(uu[t] & 0xffff0000u);
            }
        }
        for (; j < n; ++j) {
            int s = __shfl(sv, j);
            unsigned u = hp[(size_t)s * 64 + lane];
            acc.x += __uint_as_float(u << 16);
            acc.y += __uint_as_float(u & 0xffff0000u);
        }
    }
    unsigned hx = f2bf(acc.x), hy = f2bf(acc.y);
    float lx = acc.x - bf2f(hx), ly = acc.y - bf2f(hy);
    Ahi[(size_t)i * 64 + lane] = hx | (hy << 16);
    Alo[(size_t)i * 64 + lane] = f2bf(lx) | (f2bf(ly) << 16);
}

// ---------------- MFMA GEMM, split-precision bf16 (3-mfma ~ fp32 accuracy) -----

template<bool LAYER0>
__global__ __launch_bounds__(256) void gemm_kernel(
    const unsigned* __restrict__ Ahi_g, const unsigned* __restrict__ Alo_g,
    const float* __restrict__ W, const float* __restrict__ bias,
    const float* __restrict__ norm_s, const float* __restrict__ norm_d,
    const float* __restrict__ gamma, const float* __restrict__ beta,
    const float* __restrict__ rmean, const float* __restrict__ rvar,
    float* __restrict__ outf, unsigned short* __restrict__ outb)
{
    __shared__ unsigned lhi[64 * 68];   // 64 rows x 136 bf16 (pad 8)
    __shared__ unsigned llo[64 * 68];

    const int w    = threadIdx.x >> 6;
    const int lane = threadIdx.x & 63;
    const int quad = lane >> 4;
    const int l16  = lane & 15;

    // ---- B fragments (hi/lo) for this wave's 2 col-tiles, all K ----
    v8s Bhi[2][4], Blo[2][4];
    int col[2];
    #pragma unroll
    for (int ct = 0; ct < 2; ++ct) {
        col[ct] = 32 * w + 16 * ct + l16;
        #pragma unroll
        for (int q = 0; q < 4; ++q) {
            int kb = 32 * q + quad * 8;
            v8s hi8, lo8;
            #pragma unroll
            for (int kk = 0; kk < 8; ++kk) {
                float wv = W[(kb + kk) * D + col[ct]];
                unsigned h = f2bf(wv);
                hi8[kk] = (short)h;
                lo8[kk] = (short)f2bf(wv - bf2f(h));
            }
            Bhi[ct][q] = hi8;
            Blo[ct][q] = lo8;
        }
    }

    float bcol[2], s[2] = {0.f, 0.f}, sh[2] = {0.f, 0.f};
    #pragma unroll
    for (int ct = 0; ct < 2; ++ct) {
        bcol[ct] = bias[col[ct]];
        if (LAYER0) {
            s[ct]  = gamma[col[ct]] * rsqrtf(rvar[col[ct]] + BNEPS);
            sh[ct] = beta[col[ct]] - rmean[col[ct]] * s[ct];
        }
    }

    for (int row0 = blockIdx.x * 64; row0 < NN; row0 += gridDim.x * 64) {
        __syncthreads();
        for (int idx = threadIdx.x; idx < 64 * 64; idx += 256) {
            int r = idx >> 6, cp = idx & 63;
            int rw = row0 + r;
            unsigned vh = 0, vl = 0;
            if (rw < NN) {
                vh = Ahi_g[(size_t)rw * 64 + cp];
                vl = Alo_g[(size_t)rw * 64 + cp];
            }
            lhi[r * 68 + cp] = vh;
            llo[r * 68 + cp] = vl;
        }
        __syncthreads();

        #pragma unroll
        for (int rt = 0; rt < 4; ++rt) {
            v4f acc0 = {0.f, 0.f, 0.f, 0.f};
            v4f acc1 = {0.f, 0.f, 0.f, 0.f};
            #pragma unroll
            for (int q = 0; q < 4; ++q) {
                const unsigned short* ph = (const unsigned short*)lhi
                    + (rt * 16 + l16) * 136 + q * 32 + quad * 8;
                const unsigned short* pl = (const unsigned short*)llo
                    + (rt * 16 + l16) * 136 + q * 32 + quad * 8;
                v8s ahi = *(const v8s*)ph;
                v8s alo = *(const v8s*)pl;
                acc0 = __builtin_amdgcn_mfma_f32_16x16x32_bf16(ahi, Bhi[0][q], acc0, 0, 0, 0);
                acc0 = __builtin_amdgcn_mfma_f32_16x16x32_bf16(alo, Bhi[0][q], acc0, 0, 0, 0);
                acc0 = __builtin_amdgcn_mfma_f32_16x16x32_bf16(ahi, Blo[0][q], acc0, 0, 0, 0);
                acc1 = __builtin_amdgcn_mfma_f32_16x16x32_bf16(ahi, Bhi[1][q], acc1, 0, 0, 0);
                acc1 = __builtin_amdgcn_mfma_f32_16x16x32_bf16(alo, Bhi[1][q], acc1, 0, 0, 0);
                acc1 = __builtin_amdgcn_mfma_f32_16x16x32_bf16(ahi, Blo[1][q], acc1, 0, 0, 0);
            }
            #pragma unroll
            for (int r = 0; r < 4; ++r) {
                int rw = row0 + rt * 16 + quad * 4 + r;
                if (rw >= NN) continue;
                float nd = norm_d[rw];
                float o0 = acc0[r] * nd + bcol[0];
                float o1 = acc1[r] * nd + bcol[1];
                if (LAYER0) {
                    o0 = o0 * s[0] + sh[0];
                    o1 = o1 * s[1] + sh[1];
                    o0 = o0 > 0.f ? o0 : LEAKY * o0;
                    o1 = o1 > 0.f ? o1 : LEAKY * o1;
                    float ns = norm_s[rw];
                    o0 *= ns; o1 *= ns;
                    outb[(size_t)rw * D + col[0]] = (unsigned short)f2bf(o0);
                    outb[(size_t)rw * D + col[1]] = (unsigned short)f2bf(o1);
                } else {
                    outf[(size_t)rw * D + col[0]] = o0;
                    outf[(size_t)rw * D + col[1]] = o1;
                }
            }
        }
    }
}

// ---------------- launch ----------------

extern "C" void kernel_launch(void* const* d_in, const int* in_sizes, int n_in,
                              void* d_out, int out_size, void* d_ws, size_t ws_size,
                              hipStream_t stream) {
    const float* x     = (const float*)d_in[0];
    const int*   src   = (const int*)d_in[1];
    const int*   dst   = (const int*)d_in[2];
    const float* W1    = (const float*)d_in[3];
    const float* b1    = (const float*)d_in[4];
    const float* W2    = (const float*)d_in[5];
    const float* b2    = (const float*)d_in[6];
    const float* gamma = (const float*)d_in[7];
    const float* beta  = (const float*)d_in[8];
    const float* rmean = (const float*)d_in[9];
    const float* rvar  = (const float*)d_in[10];
    float* out = (float*)d_out;

    // bf16 gather-source scratch lives in d_out's first half (dead until the
    // final GEMM overwrites all of d_out with fp32 results).
    unsigned* hb = (unsigned*)d_out;                    // NN*64 u32 = 25.6 MB

    // ws layout (4B units)
    unsigned* Ahi   = (unsigned*)d_ws;                  // NN*64 u32 (bf16 hi pairs)
    unsigned* Alo   = Ahi + (size_t)NN * 64;            // NN*64 u32 (bf16 lo pairs)
    float*    norm  = (float*)(Alo + (size_t)NN * 64);  // 2N f32
    int*      deg   = (int*)(norm + 2 * NN);            // N int (out-degree)
    int*      hist  = deg + NN;                         // B*G int; row[] aliases after scanC
    int*      offs  = hist + B * G;                     // B*G int
    int*      bsum  = offs + B * G;                     // B int
    int*      boffs = bsum + B;                         // B int
    unsigned* ebuf  = (unsigned*)(boffs + B);           // NE u32
    float* norm_s = norm;
    float* norm_d = norm + NN;
    int*   row    = hist;                // aliases hist (dead after scanC)

    hipMemsetAsync(deg, 0, NN * sizeof(int), stream);

    // counting sort by dst bucket (+ fused out-degree in hist), local sort -> CSR
    hist_kernel<<<G, 256, 0, stream>>>(src, dst, deg, hist);
    scanA<<<B * G / 256, 256, 0, stream>>>(hist, bsum);
    scanB<<<1, 64, 0, stream>>>(bsum, boffs);
    scanC<<<B * G / 256, 256, 0, stream>>>(hist, boffs, offs);
    sort_kernel<<<G, 256, 0, stream>>>(src, dst, offs, ebuf);
    conv_kernel<<<(NN * 64 + 255) / 256, 256, 0, stream>>>(x, deg, norm_s, hb);
    local_sort<<<B, 256, 0, stream>>>(offs, ebuf, row, norm_d);

    const int AGG_BLOCKS = (NN + 3) / 4;
    const int GEMM_BLOCKS = 784;
    // layer 0: agg = selfloop + sum_e xs[src]  -> split bf16 hi/lo
    csr_agg<<<AGG_BLOCKS, 256, 0, stream>>>(row, (const int*)ebuf, hb, Ahi, Alo);
    gemm_kernel<true><<<GEMM_BLOCKS, 256, 0, stream>>>(Ahi, Alo, W1, b1,
                                                       norm_s, norm_d,
                                                       gamma, beta, rmean, rvar,
                                                       nullptr, (unsigned short*)hb);
    // layer 1: gather source = bf16 hs (norm_src folded)
    csr_agg<<<AGG_BLOCKS, 256, 0, stream>>>(row, (const int*)ebuf, hb, Ahi, Alo);
    gemm_kernel<false><<<GEMM_BLOCKS, 256, 0, stream>>>(Ahi, Alo, W2, b2,
                                                        norm_s, norm_d,
                                                        nullptr, nullptr, nullptr, nullptr,
                                                        out, nullptr);
}